// Round 4
// baseline (466.373 us; speedup 1.0000x reference)
//
#include <hip/hip_runtime.h>

#define DIM   2048
#define SLEN  2048
#define BATCH 2
#define NHEAD 16
#define HDIM  128
#define MROWS (BATCH*SLEN)   // 4096

typedef __attribute__((ext_vector_type(8))) __bf16 bf16x8;
typedef __attribute__((ext_vector_type(4))) float  f32x4;
typedef __attribute__((ext_vector_type(8))) unsigned short u16x8;
typedef __attribute__((ext_vector_type(4))) unsigned short u16x4;

__device__ __forceinline__ unsigned short f2bf(float f) {
  union { float f; unsigned u; } v; v.f = f;
  unsigned r = v.u + 0x7FFFu + ((v.u >> 16) & 1u);   // RTNE
  return (unsigned short)(r >> 16);
}
__device__ __forceinline__ float bf2f(unsigned short h) {
  union { unsigned u; float f; } v; v.u = ((unsigned)h) << 16;
  return v.f;
}
__device__ __forceinline__ void gload16(const void* g, void* l) {
  __builtin_amdgcn_global_load_lds(
      (const __attribute__((address_space(1))) void*)g,
      (__attribute__((address_space(3))) void*)l, 16, 0, 0);
}

// ---------------- fp32 -> bf16 convert (vectorized) ----------------
__global__ __launch_bounds__(256) void conv_f32_bf16(
    const float* __restrict__ in, unsigned short* __restrict__ out, int n4) {
  int t = blockIdx.x * 256 + threadIdx.x;
  if (t >= n4) return;
  f32x4 v = *(const f32x4*)(in + (size_t)t * 4);
  u16x4 o;
  o[0] = f2bf(v[0]); o[1] = f2bf(v[1]); o[2] = f2bf(v[2]); o[3] = f2bf(v[3]);
  *(u16x4*)(out + (size_t)t * 4) = o;
}

// ---------------- bf16 GEMM: C[M][N] = A[M][K] * Bw[N][K]^T + bias ----------------
// OUT_MODE: 0 = f32 row-major, 1 = bf16 row-major, 2 = bf16 transposed-per-batch
template<int OUT_MODE>
__global__ __launch_bounds__(256) void gemm_bt(
    const unsigned short* __restrict__ A,
    const unsigned short* __restrict__ Bw,
    const float* __restrict__ bias,
    void* __restrict__ Cout, int M, int N, int K)
{
  __shared__ __align__(16) unsigned short As[128][32];
  __shared__ __align__(16) unsigned short Bs[128][32];
  const int tid  = threadIdx.x;
  const int lane = tid & 63;
  const int wid  = tid >> 6;
  const int wr   = wid >> 1, wc = wid & 1;
  const int lrow = lane >> 4, lcol = lane & 15;
  const int row0 = blockIdx.x * 128, col0 = blockIdx.y * 128;

  f32x4 acc[4][4] = {};

  const unsigned short* Ablk = A  + (size_t)row0 * K;
  const unsigned short* Bblk = Bw + (size_t)col0 * K;
  char* AsB = (char*)&As[0][0];
  char* BsB = (char*)&Bs[0][0];

  for (int k0 = 0; k0 < K; k0 += 32) {
#pragma unroll
    for (int r = 0; r < 2; ++r) {
      int f = r * 256 + tid;
      gload16(Ablk + (size_t)(f >> 2) * K + k0 + (f & 3) * 8, AsB + (r * 256 + wid * 64) * 16);
      gload16(Bblk + (size_t)(f >> 2) * K + k0 + (f & 3) * 8, BsB + (r * 256 + wid * 64) * 16);
    }
    __syncthreads();
    bf16x8 af[4], bfv[4];
#pragma unroll
    for (int m = 0; m < 4; ++m)
      af[m] = *(const bf16x8*)&As[wr * 64 + m * 16 + lcol][lrow * 8];
#pragma unroll
    for (int n = 0; n < 4; ++n)
      bfv[n] = *(const bf16x8*)&Bs[wc * 64 + n * 16 + lcol][lrow * 8];
#pragma unroll
    for (int m = 0; m < 4; ++m)
#pragma unroll
      for (int n = 0; n < 4; ++n)
        acc[m][n] = __builtin_amdgcn_mfma_f32_16x16x32_bf16(af[m], bfv[n], acc[m][n], 0, 0, 0);
    __syncthreads();
  }

#pragma unroll
  for (int m = 0; m < 4; ++m) {
#pragma unroll
    for (int n = 0; n < 4; ++n) {
      int col = col0 + wc * 64 + n * 16 + lcol;
      float bv = bias[col];
      if (OUT_MODE == 2) {
        int row = row0 + wr * 64 + m * 16 + lrow * 4;
        u16x4 o;
#pragma unroll
        for (int j = 0; j < 4; ++j) o[j] = f2bf(acc[m][n][j] + bv);
        *(u16x4*)((unsigned short*)Cout +
                  ((size_t)((row >> 11) * DIM + col)) * SLEN + (row & (SLEN - 1))) = o;
      } else {
#pragma unroll
        for (int j = 0; j < 4; ++j) {
          int row = row0 + wr * 64 + m * 16 + lrow * 4 + j;
          float val = acc[m][n][j] + bv;
          if (OUT_MODE == 1) ((unsigned short*)Cout)[(size_t)row * N + col] = f2bf(val);
          else               ((float*)Cout)[(size_t)row * N + col] = val;
        }
      }
    }
  }
}

// ---------------- RoPE in-place on bf16 [4096][2048], optional output scale ----------------
__global__ __launch_bounds__(256) void rope_inplace(
    unsigned short* __restrict__ q,
    const float* __restrict__ cosT, const float* __restrict__ sinT, float scale) {
  int t   = blockIdx.x * 256 + threadIdx.x;
  int row = t >> 8;
  int e0  = (t & 255) * 8;
  int s   = row & (SLEN - 1);
  unsigned short* p = q + (size_t)row * DIM + e0;
  u16x8 v = *(u16x8*)p;
  f32x4 c  = *(const f32x4*)(cosT + (size_t)s * (DIM / 2) + (e0 >> 1));
  f32x4 sn = *(const f32x4*)(sinT + (size_t)s * (DIM / 2) + (e0 >> 1));
#pragma unroll
  for (int i = 0; i < 4; ++i) {
    float xe = bf2f(v[2 * i]), xo = bf2f(v[2 * i + 1]);
    float oe = (xe * c[i] - xo * sn[i]) * scale;
    float oo = (xo * c[i] + xe * sn[i]) * scale;
    v[2 * i] = f2bf(oe); v[2 * i + 1] = f2bf(oo);
  }
  *(u16x8*)p = v;
}

// ---------------- flash attention fwd ----------------
// grid (S/128, H, B), 256 thr. Wave w owns 32 q-rows (2 sub-tiles of 16).
// Swapped QK^T (lane's home q-row = lcol per sub-tile), in-register softmax,
// defer-max (THR=8). kf/vf fragments shared across the 2 q-sub-tiles.
__global__ __launch_bounds__(256) void attn_fwd(
    const unsigned short* __restrict__ Q,
    const unsigned short* __restrict__ Kg,
    const unsigned short* __restrict__ VtG,   // [(b*DIM + e)][SLEN]
    const float* __restrict__ mask,
    unsigned short* __restrict__ O)
{
  __shared__ __align__(16) unsigned short Ks[64][128];    // 16 KB
  __shared__ __align__(16) unsigned short Vts[128][64];   // 16 KB
  __shared__ __align__(16) unsigned short Ps[4][32][64];  // 16 KB per-wave P (32 q-rows)

  const int qt = blockIdx.x, h = blockIdx.y, b = blockIdx.z;
  const int tid = threadIdx.x, lane = tid & 63, wid = tid >> 6;
  const int lrow = lane >> 4, lcol = lane & 15;
  const int sx = (lcol & 7) << 4;            // read/store XOR (row = lcol-based everywhere)

  const unsigned short* Qb  = Q  + ((size_t)(b * SLEN + qt * 128 + wid * 32)) * DIM + h * HDIM;
  const unsigned short* Kb  = Kg + (size_t)(b * SLEN) * DIM + h * HDIM;
  const unsigned short* Vtb = VtG + ((size_t)(b * DIM + h * HDIM)) * SLEN;
  const float* mrow0 = mask + (size_t)(qt * 128 + wid * 32 + lcol) * SLEN;

  bf16x8 qf[2][4];
#pragma unroll
  for (int qs = 0; qs < 2; ++qs)
#pragma unroll
    for (int kk = 0; kk < 4; ++kk)
      qf[qs][kk] = *(const bf16x8*)(Qb + (size_t)(qs * 16 + lcol) * DIM + kk * 32 + lrow * 8);

  float m_run[2] = {-1e30f, -1e30f}, l_run[2] = {0.f, 0.f};
  f32x4 acc_o[2][8] = {};

  char* KsB  = (char*)&Ks[0][0];
  char* VtsB = (char*)&Vts[0][0];
  char* PsB  = (char*)&Ps[0][0][0];

  for (int kt = 0; kt < SLEN / 64; ++kt) {
    __syncthreads();  // prior iteration's LDS reads done before overwrite
#pragma unroll
    for (int r = 0; r < 4; ++r) {
      int L = r * 256 + wid * 64 + lane;
      int krow = L >> 4, kc = (L & 15) ^ (krow & 7);
      gload16(Kb + (size_t)(kt * 64 + krow) * DIM + kc * 8,
              KsB + (size_t)(r * 256 + wid * 64) * 16);
    }
#pragma unroll
    for (int r = 0; r < 4; ++r) {
      int L = r * 256 + wid * 64 + lane;
      int d = L >> 3, vc = (L & 7) ^ (d & 7);
      gload16(Vtb + (size_t)d * SLEN + kt * 64 + vc * 8,
              VtsB + (size_t)(r * 256 + wid * 64) * 16);
    }
    __syncthreads();

    // S^T = K·Q^T for both q-sub-tiles; kf shared (one read -> 2 MFMA)
    f32x4 sacc[2][4] = {};
#pragma unroll
    for (int kn = 0; kn < 4; ++kn)
#pragma unroll
      for (int kk = 0; kk < 4; ++kk) {
        bf16x8 kf = *(const bf16x8*)(KsB + (size_t)(kn * 16 + lcol) * 256
                                         + ((kk * 64 + lrow * 16) ^ sx));
        sacc[0][kn] = __builtin_amdgcn_mfma_f32_16x16x32_bf16(kf, qf[0][kk], sacc[0][kn], 0, 0, 0);
        sacc[1][kn] = __builtin_amdgcn_mfma_f32_16x16x32_bf16(kf, qf[1][kk], sacc[1][kn], 0, 0, 0);
      }

#pragma unroll
    for (int qs = 0; qs < 2; ++qs) {
      // mask add (vectorized f32x4 per kn)
      float sv[16];
#pragma unroll
      for (int kn = 0; kn < 4; ++kn) {
        f32x4 mv = *(const f32x4*)(mrow0 + (size_t)qs * 16 * SLEN + kt * 64 + kn * 16 + lrow * 4);
#pragma unroll
        for (int r = 0; r < 4; ++r) sv[kn * 4 + r] = sacc[qs][kn][r] + mv[r];
      }

      // in-lane row max + 2 shfl
      float pmax = sv[0];
#pragma unroll
      for (int i = 1; i < 16; ++i) pmax = fmaxf(pmax, sv[i]);
      pmax = fmaxf(pmax, __shfl_xor(pmax, 16, 64));
      pmax = fmaxf(pmax, __shfl_xor(pmax, 32, 64));

      // defer-max (T13)
      if (!__all(pmax - m_run[qs] <= 8.0f)) {
        float mnew = fmaxf(m_run[qs], pmax);
        float alpha = __expf(m_run[qs] - mnew);
        m_run[qs] = mnew;
        l_run[qs] *= alpha;
        float ar[4];
#pragma unroll
        for (int r = 0; r < 4; ++r) ar[r] = __shfl(alpha, lrow * 4 + r, 64);
#pragma unroll
        for (int d = 0; d < 8; ++d) {
          f32x4 t = acc_o[qs][d];
#pragma unroll
          for (int r = 0; r < 4; ++r) t[r] *= ar[r];
          acc_o[qs][d] = t;
        }
      }

      // exp + row sum
      float pv[16];
      float rsum = 0.f;
#pragma unroll
      for (int i = 0; i < 16; ++i) { float pe = __expf(sv[i] - m_run[qs]); pv[i] = pe; rsum += pe; }
      rsum += __shfl_xor(rsum, 16, 64);
      rsum += __shfl_xor(rsum, 32, 64);
      l_run[qs] += rsum;

      // P store: row = qs*16 + lcol, shorts kn*16+lrow*4+r -> u16x4 (8B, swizzle-safe)
#pragma unroll
      for (int kn = 0; kn < 4; ++kn) {
        u16x4 o;
#pragma unroll
        for (int r = 0; r < 4; ++r) o[r] = f2bf(pv[kn * 4 + r]);
        *(u16x4*)(PsB + wid * 4096 + (qs * 16 + lcol) * 128
                  + ((kn * 32 + lrow * 8) ^ sx)) = o;
      }
    }
    // no barrier: Ps[wid] written+read by the same wave (compiler orders via lgkmcnt)

    // PV: vf shared across q-sub-tiles (one read -> 2 MFMA)
    bf16x8 pf[2][2];
#pragma unroll
    for (int qs = 0; qs < 2; ++qs)
#pragma unroll
      for (int ks = 0; ks < 2; ++ks)
        pf[qs][ks] = *(const bf16x8*)(PsB + wid * 4096 + (qs * 16 + lcol) * 128
                                      + ((ks * 64 + lrow * 16) ^ sx));
#pragma unroll
    for (int d = 0; d < 8; ++d)
#pragma unroll
      for (int ks = 0; ks < 2; ++ks) {
        bf16x8 vf = *(const bf16x8*)(VtsB + (size_t)(d * 16 + lcol) * 128
                                          + ((ks * 64 + lrow * 16) ^ sx));
        acc_o[0][d] = __builtin_amdgcn_mfma_f32_16x16x32_bf16(pf[0][ks], vf, acc_o[0][d], 0, 0, 0);
        acc_o[1][d] = __builtin_amdgcn_mfma_f32_16x16x32_bf16(pf[1][ks], vf, acc_o[1][d], 0, 0, 0);
      }
  }

  // epilogue
#pragma unroll
  for (int qs = 0; qs < 2; ++qs) {
    float linv[4];
#pragma unroll
    for (int r = 0; r < 4; ++r) linv[r] = 1.0f / __shfl(l_run[qs], lrow * 4 + r, 64);
    int orow0 = b * SLEN + qt * 128 + wid * 32 + qs * 16 + lrow * 4;
#pragma unroll
    for (int d = 0; d < 8; ++d)
#pragma unroll
      for (int r = 0; r < 4; ++r) {
        float o = acc_o[qs][d][r] * linv[r];
        O[(size_t)(orow0 + r) * DIM + h * HDIM + d * 16 + lcol] = f2bf(o);
      }
  }
}

// ---------------- launch ----------------
extern "C" void kernel_launch(void* const* d_in, const int* in_sizes, int n_in,
                              void* d_out, int out_size, void* d_ws, size_t ws_size,
                              hipStream_t stream) {
  const float* x    = (const float*)d_in[0];
  const float* cosT = (const float*)d_in[1];
  const float* sinT = (const float*)d_in[2];
  const float* mask = (const float*)d_in[3];
  const float* Wq   = (const float*)d_in[4];
  const float* bq   = (const float*)d_in[5];
  const float* Wk   = (const float*)d_in[6];
  const float* bk   = (const float*)d_in[7];
  const float* Wv   = (const float*)d_in[8];
  const float* bv   = (const float*)d_in[9];
  const float* Wo   = (const float*)d_in[10];
  const float* bo   = (const float*)d_in[11];

  const size_t MB = 1u << 20;
  if (ws_size < 72 * MB) return;

  char* ws = (char*)d_ws;
  unsigned short* xb = (unsigned short*)(ws);            // 16 MB (reused as Ob after attn)
  unsigned short* qb = (unsigned short*)(ws + 16 * MB);  // 16 MB
  unsigned short* kb = (unsigned short*)(ws + 32 * MB);  // 16 MB
  unsigned short* Vt = (unsigned short*)(ws + 48 * MB);  // 16 MB (V pre-transposed per head)
  unsigned short* Wb = (unsigned short*)(ws + 64 * MB);  // 8 MB (weight slot, reused)
  unsigned short* Ob = xb;

  dim3 gGemm(MROWS / 128, DIM / 128);  // (32,16)
  const float scale = 0.08838834764831845f;  // 1/sqrt(128)

  conv_f32_bf16<<<8192, 256, 0, stream>>>(x, xb, (MROWS * DIM) / 4);
  conv_f32_bf16<<<4096, 256, 0, stream>>>(Wq, Wb, (DIM * DIM) / 4);
  gemm_bt<1><<<gGemm, 256, 0, stream>>>(xb, Wb, bq, qb, MROWS, DIM, DIM);
  conv_f32_bf16<<<4096, 256, 0, stream>>>(Wk, Wb, (DIM * DIM) / 4);
  gemm_bt<1><<<gGemm, 256, 0, stream>>>(xb, Wb, bk, kb, MROWS, DIM, DIM);
  conv_f32_bf16<<<4096, 256, 0, stream>>>(Wv, Wb, (DIM * DIM) / 4);
  gemm_bt<2><<<gGemm, 256, 0, stream>>>(xb, Wb, bv, Vt, MROWS, DIM, DIM);
  rope_inplace<<<4096, 256, 0, stream>>>(qb, cosT, sinT, scale);  // fold 1/sqrt(d) into q
  rope_inplace<<<4096, 256, 0, stream>>>(kb, cosT, sinT, 1.0f);
  attn_fwd<<<dim3(SLEN / 128, NHEAD, BATCH), 256, 0, stream>>>(qb, kb, Vt, mask, Ob);
  conv_f32_bf16<<<4096, 256, 0, stream>>>(Wo, Wb, (DIM * DIM) / 4);
  gemm_bt<0><<<gGemm, 256, 0, stream>>>(Ob, Wb, bo, d_out, MROWS, DIM, DIM);
}